// Round 11
// baseline (118.804 us; speedup 1.0000x reference)
//
#include <hip/hip_runtime.h>
#include <hip/hip_bf16.h>
#include <stdint.h>

#define N_NODES   50000
#define K_DIM     128
#define OUT_DIM   32
#define N_EDGES   1600000
#define NBKT      782                         // 64-node coarse buckets
#define CAP       3072                        // max edges/bucket (Poisson(2048), >20 sigma)
#define PADS      16                          // counter padding: 1 int per 64B line
#define AFIT      16                          // edges per thread in fill
#define ABLK      ((N_EDGES + 256*AFIT - 1) / (256*AFIT))   // 391
#define HFIT      16
#define HBLK      ((N_EDGES + 256*HFIT - 1) / (256*HFIT))   // 391

// -------- h = x @ W -> bf16 [50000,32]; block 0 zeroes padded counters ------
__global__ __launch_bounds__(256) void gemm_kernel(const float* __restrict__ x,
                                                   const float* __restrict__ w,
                                                   __hip_bfloat16* __restrict__ h,
                                                   int* __restrict__ counts_p) {
    __shared__ float wlds[K_DIM * OUT_DIM];
    const int t = threadIdx.x;
    if (blockIdx.x == 0) {
        for (int i = t; i < NBKT * PADS; i += 256) counts_p[i] = 0;
    }
    #pragma unroll
    for (int i = 0; i < (K_DIM * OUT_DIM) / 256; ++i)
        wlds[i * 256 + t] = w[i * 256 + t];
    __syncthreads();

    const int row = blockIdx.x * 8 + (t >> 5);
    const int col = t & 31;
    if (row >= N_NODES) return;

    const float4* x4 = reinterpret_cast<const float4*>(x + (size_t)row * K_DIM);
    float acc = 0.f;
    #pragma unroll
    for (int k4 = 0; k4 < K_DIM / 4; ++k4) {
        float4 xv = x4[k4];
        const int k = k4 * 4;
        acc += xv.x * wlds[(k + 0) * OUT_DIM + col];
        acc += xv.y * wlds[(k + 1) * OUT_DIM + col];
        acc += xv.z * wlds[(k + 2) * OUT_DIM + col];
        acc += xv.w * wlds[(k + 3) * OUT_DIM + col];
    }
    h[(size_t)row * OUT_DIM + col] = __float2bfloat16(acc);
}

// -------- bucket histogram: LDS-aggregated, merge into PADDED counters ------
__global__ __launch_bounds__(256) void bucket_hist(const int* __restrict__ edst,
                                                   int* __restrict__ counts_p) {
    __shared__ int cnt[NBKT];
    const int t = threadIdx.x;
    for (int i = t; i < NBKT; i += 256) cnt[i] = 0;
    __syncthreads();
    const int base = blockIdx.x * 256 * HFIT;
    #pragma unroll
    for (int k = 0; k < HFIT; ++k) {
        const int e = base + k * 256 + t;
        if (e < N_EDGES) atomicAdd(&cnt[edst[e] >> 6], 1);
    }
    __syncthreads();
    for (int i = t; i < NBKT; i += 256) {
        const int c = cnt[i];
        if (c) atomicAdd(&counts_p[i * PADS], c);   // one counter per 64B line
    }
}

// -------- scan: padded counts -> dense bases/cnts + padded cursor -----------
__global__ __launch_bounds__(1024) void bucket_scan(const int* __restrict__ counts_p,
                                                    int* __restrict__ bases,
                                                    int* __restrict__ cnts,
                                                    int* __restrict__ cursor_p) {
    __shared__ int s[1024];
    const int t = threadIdx.x;
    const int v = (t < NBKT) ? counts_p[t * PADS] : 0;
    s[t] = v;
    __syncthreads();
    #pragma unroll
    for (int d = 1; d < 1024; d <<= 1) {
        int xv = (t >= d) ? s[t - d] : 0;
        __syncthreads();
        s[t] += xv;
        __syncthreads();
    }
    if (t < NBKT) {
        const int excl = s[t] - v;
        bases[t] = excl;
        cnts[t]  = v;
        cursor_p[t * PADS] = excl;
    }
}

// -------- fill: scatter edges into coarse-bucket windows (padded cursor) ----
__global__ __launch_bounds__(256) void fill_coarse(const int*   __restrict__ esrc,
                                                   const int*   __restrict__ edst,
                                                   const float* __restrict__ ew,
                                                   int*         __restrict__ cursor_p,
                                                   uint64_t*    __restrict__ pairs) {
    __shared__ int cnt[NBKT];
    __shared__ int wbase[NBKT];
    const int t = threadIdx.x;
    for (int i = t; i < NBKT; i += 256) cnt[i] = 0;
    __syncthreads();

    uint32_t lo[AFIT], hi[AFIT];
    const int base = blockIdx.x * 256 * AFIT;
    #pragma unroll
    for (int k = 0; k < AFIT; ++k) {
        const int e = base + k * 256 + t;
        if (e < N_EDGES) {
            const uint32_t s = (uint32_t)esrc[e];
            const uint32_t d = (uint32_t)edst[e];
            lo[k] = (d << 16) | s;            // dst:16 | src:16
            hi[k] = __float_as_uint(ew[e]);
            atomicAdd(&cnt[d >> 6], 1);
        } else {
            lo[k] = 0xffffffffu;
        }
    }
    __syncthreads();
    for (int i = t; i < NBKT; i += 256) {
        const int c = cnt[i];
        if (c) wbase[i] = atomicAdd(&cursor_p[i * PADS], c);
    }
    __syncthreads();
    for (int i = t; i < NBKT; i += 256) cnt[i] = 0;   // reuse as rank
    __syncthreads();
    #pragma unroll
    for (int k = 0; k < AFIT; ++k) {
        if (lo[k] != 0xffffffffu) {
            const int b = (int)(lo[k] >> 22);          // dst >> 6
            const int r = atomicAdd(&cnt[b], 1);
            pairs[(size_t)wbase[b] + r] = ((uint64_t)hi[k] << 32) | lo[k];
        }
    }
}

// -------- sort+pull v2: single global read, dual LDS buffer, bf16x2 gathers -
__global__ __launch_bounds__(512) void sort_pull(const int*      __restrict__ bases,
                                                 const int*      __restrict__ cnts,
                                                 const uint64_t* __restrict__ pairs,
                                                 const __hip_bfloat16* __restrict__ h,
                                                 float*          __restrict__ out) {
    __shared__ uint64_t stg[CAP];             // raw bucket edges   (24 KB)
    __shared__ uint64_t stg2[CAP];            // node-sorted edges  (24 KB)
    __shared__ int lcnt[64];
    __shared__ int loff[65];
    const int b    = blockIdx.x;
    const int t    = threadIdx.x;
    const int beg  = bases[b];
    const int cnt  = cnts[b];
    const int wv   = t >> 6;                  // 8 waves
    const int lane = t & 63;
    const int c2   = lane & 15;               // column pair: cols 2*c2, 2*c2+1
    const int q    = lane >> 4;               // quarter: edge slot 0..3

    if (t < 64) lcnt[t] = 0;
    __syncthreads();

    if (cnt <= CAP) {
        // load raw pairs once (coalesced), count from LDS
        for (int i = t; i < cnt; i += 512) {
            const uint64_t p = pairs[beg + i];
            stg[i] = p;
            atomicAdd(&lcnt[(int)((p >> 16) & 63)], 1);
        }
        __syncthreads();
        if (t == 0) {
            int run = 0;
            #pragma unroll
            for (int i = 0; i < 64; ++i) { loff[i] = run; run += lcnt[i]; }
            loff[64] = run;
        }
        __syncthreads();
        if (t < 64) lcnt[t] = loff[t];        // cursor
        __syncthreads();
        for (int i = t; i < cnt; i += 512) {
            const uint64_t p = stg[i];
            const int pos = atomicAdd(&lcnt[(int)((p >> 16) & 63)], 1);
            stg2[pos] = p;
        }
        __syncthreads();
        // pull: wave wv owns local nodes wv*8..wv*8+7; 16 lanes per edge
        for (int nl = wv * 8; nl < wv * 8 + 8; ++nl) {
            const int node = (b << 6) + nl;
            if (node >= N_NODES) break;
            const int jb = loff[nl], je = loff[nl + 1];
            float ax = 0.f, ay = 0.f;
            int j = jb + q;
            for (; j + 12 < je; j += 16) {    // 4 edges per quarter in flight
                const uint64_t p0 = stg2[j];
                const uint64_t p1 = stg2[j + 4];
                const uint64_t p2 = stg2[j + 8];
                const uint64_t p3 = stg2[j + 12];
                const uint32_t v0 = *reinterpret_cast<const uint32_t*>(
                    h + (size_t)(p0 & 0xffffu) * OUT_DIM + 2 * c2);
                const uint32_t v1 = *reinterpret_cast<const uint32_t*>(
                    h + (size_t)(p1 & 0xffffu) * OUT_DIM + 2 * c2);
                const uint32_t v2 = *reinterpret_cast<const uint32_t*>(
                    h + (size_t)(p2 & 0xffffu) * OUT_DIM + 2 * c2);
                const uint32_t v3 = *reinterpret_cast<const uint32_t*>(
                    h + (size_t)(p3 & 0xffffu) * OUT_DIM + 2 * c2);
                const float w0 = __uint_as_float((uint32_t)(p0 >> 32));
                const float w1 = __uint_as_float((uint32_t)(p1 >> 32));
                const float w2 = __uint_as_float((uint32_t)(p2 >> 32));
                const float w3 = __uint_as_float((uint32_t)(p3 >> 32));
                ax += w0 * __uint_as_float(v0 << 16);
                ay += w0 * __uint_as_float(v0 & 0xffff0000u);
                ax += w1 * __uint_as_float(v1 << 16);
                ay += w1 * __uint_as_float(v1 & 0xffff0000u);
                ax += w2 * __uint_as_float(v2 << 16);
                ay += w2 * __uint_as_float(v2 & 0xffff0000u);
                ax += w3 * __uint_as_float(v3 << 16);
                ay += w3 * __uint_as_float(v3 & 0xffff0000u);
            }
            for (; j < je; j += 4) {          // tail: 1 edge per quarter step
                const uint64_t p = stg2[j];
                const uint32_t v = *reinterpret_cast<const uint32_t*>(
                    h + (size_t)(p & 0xffffu) * OUT_DIM + 2 * c2);
                const float w = __uint_as_float((uint32_t)(p >> 32));
                ax += w * __uint_as_float(v << 16);
                ay += w * __uint_as_float(v & 0xffff0000u);
            }
            // reduce across the 4 quarters
            ax += __shfl_xor(ax, 16, 64);  ay += __shfl_xor(ay, 16, 64);
            ax += __shfl_xor(ax, 32, 64);  ay += __shfl_xor(ay, 32, 64);
            if (q == 0) {                     // 16 lanes write float2 = 128B row
                float2* o2 = reinterpret_cast<float2*>(out + (size_t)node * OUT_DIM);
                o2[c2] = make_float2(ax, ay);
            }
        }
    } else {
        // safety path (statistically never taken): predicated global scan
        for (int nl = wv * 8; nl < wv * 8 + 8; ++nl) {
            const int node = (b << 6) + nl;
            if (node >= N_NODES) break;
            float ax = 0.f, ay = 0.f;
            for (int j = q; j < cnt; j += 4) {
                const uint64_t p = pairs[beg + j];
                if ((int)((p >> 16) & 63) == nl) {
                    const uint32_t v = *reinterpret_cast<const uint32_t*>(
                        h + (size_t)(p & 0xffffu) * OUT_DIM + 2 * c2);
                    const float w = __uint_as_float((uint32_t)(p >> 32));
                    ax += w * __uint_as_float(v << 16);
                    ay += w * __uint_as_float(v & 0xffff0000u);
                }
            }
            ax += __shfl_xor(ax, 16, 64);  ay += __shfl_xor(ay, 16, 64);
            ax += __shfl_xor(ax, 32, 64);  ay += __shfl_xor(ay, 32, 64);
            if (q == 0) {
                float2* o2 = reinterpret_cast<float2*>(out + (size_t)node * OUT_DIM);
                o2[c2] = make_float2(ax, ay);
            }
        }
    }
}

// -------- fallback: atomic scatter (bf16 h) --------
__global__ __launch_bounds__(256) void scatter_kernel(const int*   __restrict__ esrc,
                                                      const int*   __restrict__ edst,
                                                      const float* __restrict__ ew,
                                                      const __hip_bfloat16* __restrict__ h,
                                                      float*       out) {
    const long long gid = (long long)blockIdx.x * blockDim.x + threadIdx.x;
    const int e   = (int)(gid >> 5);
    const int col = (int)(gid & 31);
    if (e >= N_EDGES) return;
    atomicAdd(out + (size_t)edst[e] * OUT_DIM + col,
              ew[e] * __bfloat162float(h[(size_t)esrc[e] * OUT_DIM + col]));
}

extern "C" void kernel_launch(void* const* d_in, const int* in_sizes, int n_in,
                              void* d_out, int out_size, void* d_ws, size_t ws_size,
                              hipStream_t stream) {
    const float* x    = (const float*)d_in[0];
    const float* w    = (const float*)d_in[1];
    const int*   esrc = (const int*)d_in[2];
    const int*   edst = (const int*)d_in[3];
    const float* ew   = (const float*)d_in[4];
    float*       out  = (float*)d_out;

    const size_t PAIRS_B = (size_t)N_EDGES * 8;            // 12,800,000
    const size_t H_B     = (size_t)N_NODES * OUT_DIM * 2;  //  3,200,000 (bf16)
    const size_t CPAD_B  = (size_t)NBKT * PADS * 4;        //     50,048
    const size_t DEN_B   = (size_t)NBKT * 4;               //      3,128
    const size_t REQ     = PAIRS_B + H_B + 2 * CPAD_B + 2 * DEN_B;

    uint64_t*        pairs    = (uint64_t*)d_ws;
    __hip_bfloat16*  h        = (__hip_bfloat16*)((char*)d_ws + PAIRS_B);
    int*             counts_p = (int*)((char*)d_ws + PAIRS_B + H_B);
    int*             cursor_p = counts_p + NBKT * PADS;
    int*             bases    = cursor_p + NBKT * PADS;
    int*             cnts     = bases + NBKT;

    if (ws_size >= REQ) {
        gemm_kernel<<<(N_NODES + 7) / 8, 256, 0, stream>>>(x, w, h, counts_p);
        bucket_hist<<<HBLK, 256, 0, stream>>>(edst, counts_p);
        bucket_scan<<<1, 1024, 0, stream>>>(counts_p, bases, cnts, cursor_p);
        fill_coarse<<<ABLK, 256, 0, stream>>>(esrc, edst, ew, cursor_p, pairs);
        sort_pull<<<NBKT, 512, 0, stream>>>(bases, cnts, pairs, h, out);
    } else {
        __hip_bfloat16* hf = (__hip_bfloat16*)d_ws;
        (void)hipMemsetAsync(d_out, 0, (size_t)out_size * sizeof(float), stream);
        gemm_kernel<<<(N_NODES + 7) / 8, 256, 0, stream>>>(x, w, hf,
                                                           (int*)((char*)d_ws + H_B));
        const long long total = (long long)N_EDGES * OUT_DIM;
        scatter_kernel<<<(int)((total + 255) / 256), 256, 0, stream>>>(esrc, edst, ew, hf, out);
    }
}

// Round 12
// 80.963 us; speedup vs baseline: 1.4674x; 1.4674x over previous
//
#include <hip/hip_runtime.h>
#include <hip/hip_bf16.h>
#include <stdint.h>

#define N_NODES   50000
#define K_DIM     128
#define OUT_DIM   32
#define N_EDGES   1600000
#define NBKT      782                         // 64-node coarse buckets
#define CAP       3072                        // fixed window stride (mean 2046 + 22 sigma)
#define AFIT      16                          // edges per thread in fill
#define ABLK      ((N_EDGES + 256*AFIT - 1) / (256*AFIT))   // 391

// -------- K1: h = x @ W -> bf16 [50000,32]; block 0 zeroes bucket cursors ---
__global__ __launch_bounds__(256) void gemm_kernel(const float* __restrict__ x,
                                                   const float* __restrict__ w,
                                                   __hip_bfloat16* __restrict__ h,
                                                   int* __restrict__ cursor) {
    __shared__ float wlds[K_DIM * OUT_DIM];
    const int t = threadIdx.x;
    if (blockIdx.x == 0) {
        for (int i = t; i < NBKT; i += 256) cursor[i] = 0;
    }
    #pragma unroll
    for (int i = 0; i < (K_DIM * OUT_DIM) / 256; ++i)
        wlds[i * 256 + t] = w[i * 256 + t];
    __syncthreads();

    const int row = blockIdx.x * 8 + (t >> 5);
    const int col = t & 31;
    if (row >= N_NODES) return;

    const float4* x4 = reinterpret_cast<const float4*>(x + (size_t)row * K_DIM);
    float acc = 0.f;
    #pragma unroll
    for (int k4 = 0; k4 < K_DIM / 4; ++k4) {
        float4 xv = x4[k4];
        const int k = k4 * 4;
        acc += xv.x * wlds[(k + 0) * OUT_DIM + col];
        acc += xv.y * wlds[(k + 1) * OUT_DIM + col];
        acc += xv.z * wlds[(k + 2) * OUT_DIM + col];
        acc += xv.w * wlds[(k + 3) * OUT_DIM + col];
    }
    h[(size_t)row * OUT_DIM + col] = __float2bfloat16(acc);
}

// -------- K2: scatter edges into FIXED-STRIDE bucket windows ----------------
// No histogram/scan needed: rank comes from a per-bucket global cursor.
__global__ __launch_bounds__(256) void fill_direct(const int*   __restrict__ esrc,
                                                   const int*   __restrict__ edst,
                                                   const float* __restrict__ ew,
                                                   int*         __restrict__ cursor,
                                                   uint64_t*    __restrict__ pairs) {
    __shared__ int cnt[NBKT];
    __shared__ int wbase[NBKT];
    const int t = threadIdx.x;
    for (int i = t; i < NBKT; i += 256) cnt[i] = 0;
    __syncthreads();

    uint32_t lo[AFIT], hi[AFIT];
    const int base = blockIdx.x * 256 * AFIT;
    #pragma unroll
    for (int k = 0; k < AFIT; ++k) {
        const int e = base + k * 256 + t;
        if (e < N_EDGES) {
            const uint32_t s = (uint32_t)esrc[e];
            const uint32_t d = (uint32_t)edst[e];
            lo[k] = (d << 16) | s;            // dst:16 | src:16
            hi[k] = __float_as_uint(ew[e]);
            atomicAdd(&cnt[d >> 6], 1);
        } else {
            lo[k] = 0xffffffffu;
        }
    }
    __syncthreads();
    for (int i = t; i < NBKT; i += 256) {
        const int c = cnt[i];
        if (c) wbase[i] = atomicAdd(&cursor[i], c);
    }
    __syncthreads();
    for (int i = t; i < NBKT; i += 256) cnt[i] = 0;   // reuse as block-local rank
    __syncthreads();
    #pragma unroll
    for (int k = 0; k < AFIT; ++k) {
        if (lo[k] != 0xffffffffu) {
            const int b = (int)(lo[k] >> 22);          // dst >> 6
            const int r = atomicAdd(&cnt[b], 1);
            const int pos = wbase[b] + r;
            if (pos < CAP)                              // overflow guard (P ~ 0)
                pairs[(size_t)b * CAP + pos] = ((uint64_t)hi[k] << 32) | lo[k];
        }
    }
}

// -------- K3: fused sort+pull per bucket (R10-proven v1 logic) --------------
__global__ __launch_bounds__(512) void sort_pull(const int*      __restrict__ cursor,
                                                 const uint64_t* __restrict__ pairs,
                                                 const __hip_bfloat16* __restrict__ h,
                                                 float*          __restrict__ out) {
    __shared__ uint64_t stg[CAP];             // 24 KB
    __shared__ int lcnt[64];
    __shared__ int loff[65];
    const int b    = blockIdx.x;
    const int t    = threadIdx.x;
    const size_t beg = (size_t)b * CAP;
    const int cnt  = min(cursor[b], CAP);
    const int wv   = t >> 6;                  // 8 waves
    const int lane = t & 63;
    const int col  = lane & 31;
    const int half = lane >> 5;

    if (t < 64) lcnt[t] = 0;
    __syncthreads();

    // phase 1: count per local node (first global read of window)
    for (int i = t; i < cnt; i += 512)
        atomicAdd(&lcnt[(int)((pairs[beg + i] >> 16) & 63)], 1);
    __syncthreads();
    if (t == 0) {
        int run = 0;
        #pragma unroll
        for (int i = 0; i < 64; ++i) { loff[i] = run; run += lcnt[i]; }
        loff[64] = run;
    }
    __syncthreads();
    if (t < 64) lcnt[t] = loff[t];            // cursor
    __syncthreads();
    // phase 2: sort into LDS (second read is L2-hot)
    for (int i = t; i < cnt; i += 512) {
        const uint64_t p = pairs[beg + i];
        const int pos = atomicAdd(&lcnt[(int)((p >> 16) & 63)], 1);
        stg[pos] = p;
    }
    __syncthreads();
    // phase 3: pull — wave wv owns local nodes wv*8..wv*8+7
    for (int nl = wv * 8; nl < wv * 8 + 8; ++nl) {
        const int node = (b << 6) + nl;
        if (node >= N_NODES) break;
        const int jb = loff[nl], je = loff[nl + 1];
        float acc = 0.f;
        int j = jb + half;
        for (; j + 6 < je; j += 8) {
            const uint64_t p0 = stg[j];
            const uint64_t p1 = stg[j + 2];
            const uint64_t p2 = stg[j + 4];
            const uint64_t p3 = stg[j + 6];
            const float a0 = __bfloat162float(h[(size_t)(p0 & 0xffffu) * OUT_DIM + col]);
            const float a1 = __bfloat162float(h[(size_t)(p1 & 0xffffu) * OUT_DIM + col]);
            const float a2 = __bfloat162float(h[(size_t)(p2 & 0xffffu) * OUT_DIM + col]);
            const float a3 = __bfloat162float(h[(size_t)(p3 & 0xffffu) * OUT_DIM + col]);
            acc += __uint_as_float((uint32_t)(p0 >> 32)) * a0;
            acc += __uint_as_float((uint32_t)(p1 >> 32)) * a1;
            acc += __uint_as_float((uint32_t)(p2 >> 32)) * a2;
            acc += __uint_as_float((uint32_t)(p3 >> 32)) * a3;
        }
        for (; j < je; j += 2) {
            const uint64_t p = stg[j];
            acc += __uint_as_float((uint32_t)(p >> 32)) *
                   __bfloat162float(h[(size_t)(p & 0xffffu) * OUT_DIM + col]);
        }
        acc += __shfl_xor(acc, 32, 64);
        if (half == 0) out[(size_t)node * OUT_DIM + col] = acc;
    }
}

// -------- fallback: atomic scatter (bf16 h) --------
__global__ __launch_bounds__(256) void scatter_kernel(const int*   __restrict__ esrc,
                                                      const int*   __restrict__ edst,
                                                      const float* __restrict__ ew,
                                                      const __hip_bfloat16* __restrict__ h,
                                                      float*       out) {
    const long long gid = (long long)blockIdx.x * blockDim.x + threadIdx.x;
    const int e   = (int)(gid >> 5);
    const int col = (int)(gid & 31);
    if (e >= N_EDGES) return;
    atomicAdd(out + (size_t)edst[e] * OUT_DIM + col,
              ew[e] * __bfloat162float(h[(size_t)esrc[e] * OUT_DIM + col]));
}

extern "C" void kernel_launch(void* const* d_in, const int* in_sizes, int n_in,
                              void* d_out, int out_size, void* d_ws, size_t ws_size,
                              hipStream_t stream) {
    const float* x    = (const float*)d_in[0];
    const float* w    = (const float*)d_in[1];
    const int*   esrc = (const int*)d_in[2];
    const int*   edst = (const int*)d_in[3];
    const float* ew   = (const float*)d_in[4];
    float*       out  = (float*)d_out;

    const size_t PAIRS_B = (size_t)NBKT * CAP * 8;         // 19,218,432
    const size_t H_B     = (size_t)N_NODES * OUT_DIM * 2;  //  3,200,000 (bf16)
    const size_t CUR_B   = (size_t)NBKT * 4;               //      3,128
    const size_t REQ     = PAIRS_B + H_B + CUR_B;

    uint64_t*        pairs  = (uint64_t*)d_ws;
    __hip_bfloat16*  h      = (__hip_bfloat16*)((char*)d_ws + PAIRS_B);
    int*             cursor = (int*)((char*)d_ws + PAIRS_B + H_B);

    if (ws_size >= REQ) {
        gemm_kernel<<<(N_NODES + 7) / 8, 256, 0, stream>>>(x, w, h, cursor);
        fill_direct<<<ABLK, 256, 0, stream>>>(esrc, edst, ew, cursor, pairs);
        sort_pull<<<NBKT, 512, 0, stream>>>(cursor, pairs, h, out);
    } else {
        __hip_bfloat16* hf = (__hip_bfloat16*)d_ws;
        int* cur = (int*)((char*)d_ws + H_B);
        (void)hipMemsetAsync(d_out, 0, (size_t)out_size * sizeof(float), stream);
        gemm_kernel<<<(N_NODES + 7) / 8, 256, 0, stream>>>(x, w, hf, cur);
        const long long total = (long long)N_EDGES * OUT_DIM;
        scatter_kernel<<<(int)((total + 255) / 256), 256, 0, stream>>>(esrc, edst, ew, hf, out);
    }
}